// Round 7
// baseline (170.905 us; speedup 1.0000x reference)
//
#include <hip/hip_runtime.h>

// ---------------------------------------------------------------------------
// AttentionLayer: q=relu(x1@Wq+bq)/8, k=relu(x2@Wk+bk), v=relu(x2@Wv+bv)
//   out = softmax(mask(q@k^T)) @ v          B=4, S=4096, D=512, dk=64
// Round 7:
//  proj:  REWRITE — no LDS in main loop (X has zero cross-wave reuse; LDS
//         staging was pure overhead). A-frags stream global f32->f16 regs,
//         B-frags from L2-hot WtT. Barrier-free; LDS only for V-transpose
//         epilogue.
//  attn:  r6 swapped-operand structure + s_setprio around MFMA clusters.
//  prep/combine: unchanged.
// Verified layouts (r2..r6, absmax 0.0156):
//   A/B frag: row|col = lane&15, k = 8*(lane>>4)+e   (one b128 per frag)
//   C/D frag: col = lane&15,     row = 4*(lane>>4)+r
//   mfma(A,B): D[i][j] = sum_k A[i][k]*B[j][k]
// ---------------------------------------------------------------------------

typedef __attribute__((ext_vector_type(8))) _Float16 f16x8;
typedef __attribute__((ext_vector_type(4))) float f32x4;
typedef __attribute__((ext_vector_type(8))) unsigned short us8;
typedef __attribute__((ext_vector_type(4))) unsigned short us4;

#define AS1 __attribute__((address_space(1)))
#define AS3 __attribute__((address_space(3)))

__device__ __forceinline__ void gload16(const void* g, void* l) {
  __builtin_amdgcn_global_load_lds((const AS1 unsigned int*)g,
                                   (AS3 unsigned int*)l, 16, 0, 0);
}

__device__ __forceinline__ unsigned short f2h(float f) {
  _Float16 h = (_Float16)f;  // RNE
  return __builtin_bit_cast(unsigned short, h);
}
__device__ __forceinline__ float h2f(unsigned short u) {
  return (float)__builtin_bit_cast(_Float16, u);
}
__device__ __forceinline__ f16x8 us2h(us8 v) {
  return __builtin_bit_cast(f16x8, v);
}

#define S_LEN 4096
#define NROW 16384  // B*S
#define CCH 8       // kv-steps per partial unit
#define NPMAX 8

// ---------------------------------------------------------------------------
// prep: W[512][64] f32 -> WtT[p][64 n][512 k] f16. grid (8 kchunks, 3 mats).
// ---------------------------------------------------------------------------
__global__ __launch_bounds__(256) void prep_kernel(
    const float* __restrict__ Wq, const float* __restrict__ Wk,
    const float* __restrict__ Wv, unsigned short* __restrict__ wtT) {
  const int kc = blockIdx.x, p = blockIdx.y;
  const float* __restrict__ W = (p == 0) ? Wq : (p == 1) ? Wk : Wv;
  __shared__ unsigned short T[64][72];
  const int t = threadIdx.x;
#pragma unroll
  for (int i = 0; i < 4; i++) {
    int f = t + 256 * i;  // 0..1023 float4 slots (64 k x 16)
    int kk = f >> 4, c4 = (f & 15) << 2;
    float4 v4 = *(const float4*)&W[(size_t)(kc * 64 + kk) * 64 + c4];
    T[c4 + 0][kk] = f2h(v4.x);
    T[c4 + 1][kk] = f2h(v4.y);
    T[c4 + 2][kk] = f2h(v4.z);
    T[c4 + 3][kk] = f2h(v4.w);
  }
  __syncthreads();
  const int n = t >> 2, q4 = (t & 3) << 4;
  us8 o0, o1;
#pragma unroll
  for (int e = 0; e < 8; e++) o0[e] = T[n][q4 + e];
#pragma unroll
  for (int e = 0; e < 8; e++) o1[e] = T[n][q4 + 8 + e];
  unsigned short* dst = &wtT[((size_t)p * 64 + n) * 512 + kc * 64 + q4];
  *(us8*)&dst[0] = o0;
  *(us8*)&dst[8] = o1;
}

// ---------------------------------------------------------------------------
// proj: grid (512 row-tiles of 32, 2 kinds), 128 threads = 2 waves.
// Barrier-free streaming: A direct global->reg, B direct from WtT (L2).
// kind 0: q from x1.  kind 1: k AND v from x2 (x2 read once).
// ---------------------------------------------------------------------------
__global__ __launch_bounds__(128) void proj_kernel(
    const float* __restrict__ x1, const float* __restrict__ x2,
    const unsigned short* __restrict__ wtT, const float* __restrict__ bq,
    const float* __restrict__ bk, const float* __restrict__ bv,
    unsigned short* __restrict__ qo, unsigned short* __restrict__ ko,
    unsigned short* __restrict__ vto) {
  const int kind = blockIdx.y;
  const float* __restrict__ X = kind ? x2 : x1;
  const int row0 = blockIdx.x * 32;

  __shared__ __align__(16) unsigned short TB[32 * 72];  // V-transpose epilogue

  const int t = threadIdx.x, ln = t & 63, w = t >> 6, lm = ln & 15, lg = ln >> 4;

  f32x4 acc0[4], acc1[4];
#pragma unroll
  for (int nt = 0; nt < 4; nt++)
#pragma unroll
    for (int e = 0; e < 4; e++) { acc0[nt][e] = 0.0f; acc1[nt][e] = 0.0f; }

  const unsigned short* __restrict__ wt0 =
      wtT + (size_t)(kind ? 1 : 0) * 64 * 512;
  const unsigned short* __restrict__ wt1 = wtT + (size_t)2 * 64 * 512;
  const float* __restrict__ xrow = &X[(size_t)(row0 + 16 * w + lm) * 512];

#pragma unroll 2
  for (int kc = 0; kc < 8; kc++) {
    // A fragments: 2 halves x 2 float4, coalesced 128B per (row,half) group
    f16x8 af[2];
#pragma unroll
    for (int h = 0; h < 2; h++) {
      const float* ap = &xrow[kc * 64 + 32 * h + 8 * lg];
      float4 a0 = *(const float4*)ap;
      float4 a1 = *(const float4*)(ap + 4);
      f16x8 v;
      v[0] = (_Float16)a0.x; v[1] = (_Float16)a0.y;
      v[2] = (_Float16)a0.z; v[3] = (_Float16)a0.w;
      v[4] = (_Float16)a1.x; v[5] = (_Float16)a1.y;
      v[6] = (_Float16)a1.z; v[7] = (_Float16)a1.w;
      af[h] = v;
    }
#pragma unroll
    for (int nt = 0; nt < 4; nt++) {
      const size_t rb = (size_t)(16 * nt + lm) * 512 + kc * 64 + 8 * lg;
      us8 b00 = *(const us8*)&wt0[rb];
      us8 b01 = *(const us8*)&wt0[rb + 32];
      acc0[nt] = __builtin_amdgcn_mfma_f32_16x16x32_f16(af[0], us2h(b00), acc0[nt], 0, 0, 0);
      acc0[nt] = __builtin_amdgcn_mfma_f32_16x16x32_f16(af[1], us2h(b01), acc0[nt], 0, 0, 0);
      if (kind) {
        us8 b10 = *(const us8*)&wt1[rb];
        us8 b11 = *(const us8*)&wt1[rb + 32];
        acc1[nt] = __builtin_amdgcn_mfma_f32_16x16x32_f16(af[0], us2h(b10), acc1[nt], 0, 0, 0);
        acc1[nt] = __builtin_amdgcn_mfma_f32_16x16x32_f16(af[1], us2h(b11), acc1[nt], 0, 0, 0);
      }
    }
  }

  // epilogue
  if (kind == 0) {
#pragma unroll
    for (int nt = 0; nt < 4; nt++)
#pragma unroll
      for (int r = 0; r < 4; r++) {
        int row = row0 + 16 * w + 4 * lg + r;
        int col = 16 * nt + lm;
        float v = fmaxf(acc0[nt][r] + bq[col], 0.0f) * 0.125f;
        qo[(size_t)row * 64 + col] = f2h(v);
      }
  } else {
#pragma unroll
    for (int nt = 0; nt < 4; nt++)
#pragma unroll
      for (int r = 0; r < 4; r++) {
        int row = row0 + 16 * w + 4 * lg + r;
        int col = 16 * nt + lm;
        float v = fmaxf(acc0[nt][r] + bk[col], 0.0f);
        ko[(size_t)row * 64 + col] = f2h(v);
      }
    // v: transpose via LDS, coalesced us8 stores to vT
#pragma unroll
    for (int nt = 0; nt < 4; nt++)
#pragma unroll
      for (int r = 0; r < 4; r++) {
        float v = fmaxf(acc1[nt][r] + bv[16 * nt + lm], 0.0f);
        TB[(16 * w + 4 * lg + r) * 72 + 16 * nt + lm] = f2h(v);
      }
    __syncthreads();
    const int d = t >> 1, s0 = (t & 1) << 4;
    us8 o0, o1;
#pragma unroll
    for (int e = 0; e < 8; e++) o0[e] = TB[(s0 + e) * 72 + d];
#pragma unroll
    for (int e = 0; e < 8; e++) o1[e] = TB[(s0 + 8 + e) * 72 + d];
    const int batch = row0 >> 12, sl = row0 & 4095;
    unsigned short* vp = &vto[((size_t)batch * 64 + d) * S_LEN + sl + s0];
    *(us8*)&vp[0] = o0;
    *(us8*)&vp[8] = o1;
  }
}

// ---------------------------------------------------------------------------
// attn partial (SWAPPED): grid (64 qt, 8 units, 4 batch), 256 thr.
// scT[key][q] = mfma(K,Q): lane lm owns q-row 16w+lm; keys 16nt+4lg+r.
// accOT[d][q] = mfma(V,P): lane-local m/l/rescale.
// ---------------------------------------------------------------------------
__global__ __launch_bounds__(256) void attn_part(
    const unsigned short* __restrict__ q, const unsigned short* __restrict__ k,
    const unsigned short* __restrict__ vT, const int* __restrict__ amask,
    unsigned short* __restrict__ pO, float* __restrict__ pml) {
  const int qt = blockIdx.x, j = blockIdx.y, b = blockIdx.z;
  const int mask = *amask;
  const int sb = j * CCH;
  if (mask && sb > qt) return;
  const int se0 = sb + CCH - 1;
  const int se = mask ? ((qt < se0) ? qt : se0) : se0;

  const int t = threadIdx.x, ln = t & 63, w = t >> 6, lm = ln & 15, lg = ln >> 4;

  __shared__ __align__(16) unsigned short KB[2][4096];  // 64 rows x 8 slots
  __shared__ __align__(16) unsigned short VB[2][4096];
  __shared__ __align__(16) unsigned short Ps[4][16][72];

  const unsigned short* __restrict__ qb = q + (size_t)b * S_LEN * 64;
  const unsigned short* __restrict__ kb = k + (size_t)b * S_LEN * 64;
  const unsigned short* __restrict__ vb = vT + (size_t)b * 64 * S_LEN;

  // Q fragments (persistent; B-operand: row=q=lm, k=8lg+e)
  const size_t qoff = (size_t)(qt * 64 + 16 * w + lm) * 64;
  f16x8 qf0 = *(const f16x8*)&qb[qoff + 8 * lg];
  f16x8 qf1 = *(const f16x8*)&qb[qoff + 32 + 8 * lg];

  // stage tile s into buffer bi: wave w stages chunks 2w,2w+1 of K and V
  const int rr = ln >> 3;               // row-within-chunk
  const int sg = (ln & 7) ^ (rr & 7);   // pre-swizzled source slot
  auto STAGE = [&](int s, int bi) {
    const int kv0 = s * 64;
#pragma unroll
    for (int cc = 0; cc < 2; cc++) {
      int c = 2 * w + cc;
      int r = 8 * c + rr;
      gload16(&kb[(size_t)(kv0 + r) * 64 + sg * 8], &KB[bi][c * 512]);
      gload16(&vb[(size_t)r * S_LEN + kv0 + sg * 8], &VB[bi][c * 512]);
    }
  };

  f32x4 accO[4];  // O^T: accO[dt][r] = O[q=16w+lm][d=16dt+4lg+r]
#pragma unroll
  for (int dt = 0; dt < 4; dt++)
#pragma unroll
    for (int e = 0; e < 4; e++) accO[dt][e] = 0.0f;
  float m0 = -1e30f, l0 = 0.0f;  // lane-local (q = 16w+lm)

  const int sx = lm & 7;
  STAGE(sb, 0);
  for (int s = sb; s <= se; s++) {
    const int bi = (s - sb) & 1;
    if (s < se) {
      STAGE(s + 1, bi ^ 1);
      asm volatile("s_waitcnt vmcnt(4)" ::: "memory");
    } else {
      asm volatile("s_waitcnt vmcnt(0)" ::: "memory");
    }
    __builtin_amdgcn_sched_barrier(0);
    __builtin_amdgcn_s_barrier();

    // QK^T swapped: scT[nt][r] = S[key=16nt+4lg+r][q=16w+lm]
    f32x4 sc[4];
    __builtin_amdgcn_s_setprio(1);
#pragma unroll
    for (int nt = 0; nt < 4; nt++) {
#pragma unroll
      for (int e = 0; e < 4; e++) sc[nt][e] = 0.0f;
      const int R = 16 * nt + lm;
      f16x8 kf0 = *(const f16x8*)&KB[bi][R * 64 + (lg ^ sx) * 8];
      f16x8 kf1 = *(const f16x8*)&KB[bi][R * 64 + ((4 + lg) ^ sx) * 8];
      sc[nt] = __builtin_amdgcn_mfma_f32_16x16x32_f16(kf0, qf0, sc[nt], 0, 0, 0);
      sc[nt] = __builtin_amdgcn_mfma_f32_16x16x32_f16(kf1, qf1, sc[nt], 0, 0, 0);
    }
    __builtin_amdgcn_s_setprio(0);

    if (mask && s == qt) {  // diagonal: key_local > q_local
#pragma unroll
      for (int nt = 0; nt < 4; nt++)
#pragma unroll
        for (int r = 0; r < 4; r++)
          if (16 * nt + 4 * lg + r > 16 * w + lm) sc[nt][r] = -1e30f;
    }

    // lane-local row max over 16 scores + butterfly over lg (xor 16,32)
    float mx = fmaxf(fmaxf(fmaxf(sc[0][0], sc[0][1]), fmaxf(sc[0][2], sc[0][3])),
                     fmaxf(fmaxf(sc[1][0], sc[1][1]), fmaxf(sc[1][2], sc[1][3])));
    float mx2 = fmaxf(fmaxf(fmaxf(sc[2][0], sc[2][1]), fmaxf(sc[2][2], sc[2][3])),
                      fmaxf(fmaxf(sc[3][0], sc[3][1]), fmaxf(sc[3][2], sc[3][3])));
    mx = fmaxf(mx, mx2);
    mx = fmaxf(mx, __shfl_xor(mx, 16));
    mx = fmaxf(mx, __shfl_xor(mx, 32));
    const float mn = fmaxf(m0, mx);
    const float fs = __expf(m0 - mn);
    m0 = mn;

    float pv[4][4];
    float su = 0.0f;
#pragma unroll
    for (int nt = 0; nt < 4; nt++)
#pragma unroll
      for (int r = 0; r < 4; r++) {
        pv[nt][r] = __expf(sc[nt][r] - mn);
        su += pv[nt][r];
      }
    su += __shfl_xor(su, 16);
    su += __shfl_xor(su, 32);
    l0 = l0 * fs + su;
#pragma unroll
    for (int dt = 0; dt < 4; dt++)
#pragma unroll
      for (int e = 0; e < 4; e++) accO[dt][e] *= fs;

    // P -> Ps[q=lm][key]: 4 packed b64 writes (wave-local, no barrier)
#pragma unroll
    for (int nt = 0; nt < 4; nt++) {
      us4 w4;
#pragma unroll
      for (int r = 0; r < 4; r++) w4[r] = f2h(pv[nt][r]);
      *(us4*)&Ps[w][lm][16 * nt + 4 * lg] = w4;
    }

    // PV swapped: accO[dt] = mfma(V^T-frag, P-frag): D[d=16dt+4lg+r][q=lm]
    f16x8 pf0 = *(const f16x8*)&Ps[w][lm][8 * lg];
    f16x8 pf1 = *(const f16x8*)&Ps[w][lm][32 + 8 * lg];
    __builtin_amdgcn_s_setprio(1);
#pragma unroll
    for (int dt = 0; dt < 4; dt++) {
      const int R = 16 * dt + lm;
      f16x8 vf0 = *(const f16x8*)&VB[bi][R * 64 + (lg ^ sx) * 8];
      f16x8 vf1 = *(const f16x8*)&VB[bi][R * 64 + ((4 + lg) ^ sx) * 8];
      accO[dt] = __builtin_amdgcn_mfma_f32_16x16x32_f16(vf0, pf0, accO[dt], 0, 0, 0);
      accO[dt] = __builtin_amdgcn_mfma_f32_16x16x32_f16(vf1, pf1, accO[dt], 0, 0, 0);
    }
    __builtin_amdgcn_s_setprio(0);
    __builtin_amdgcn_sched_barrier(0);
    __builtin_amdgcn_s_barrier();
  }

  // store partial: O rows q=16w+lm, cols d=16dt+4lg+{0..3} (us4 stores)
  const size_t ub = (size_t)(b * 64 + qt) * NPMAX + j;
  unsigned short* __restrict__ Op = pO + ub * 4096;
#pragma unroll
  for (int dt = 0; dt < 4; dt++) {
    us4 o4;
#pragma unroll
    for (int r = 0; r < 4; r++) o4[r] = f2h(accO[dt][r]);
    *(us4*)&Op[(16 * w + lm) * 64 + 16 * dt + 4 * lg] = o4;
  }
  if (lg == 0) {
    float* __restrict__ mlp = pml + ub * 128;
    mlp[(16 * w + lm) * 2 + 0] = m0;
    mlp[(16 * w + lm) * 2 + 1] = l0;
  }
}

// ---------------------------------------------------------------------------
// combine: grid (64 qt, 4 colgroups, 4 batch), 256 thr; thread owns 4 cols
// of one row. Merges partials with global max, normalizes.
// ---------------------------------------------------------------------------
__global__ __launch_bounds__(256) void combine_kernel(
    const unsigned short* __restrict__ pO, const float* __restrict__ pml,
    const int* __restrict__ amask, float* __restrict__ out) {
  const int qt = blockIdx.x, cg = blockIdx.y, b = blockIdx.z;
  const int mask = *amask;
  const int np = mask ? (qt / CCH + 1) : NPMAX;
  const int t = threadIdx.x;
  const int row = t >> 2, c = ((t & 3) << 2) + (cg << 4);
  const size_t base = (size_t)(b * 64 + qt) * NPMAX;

  float M = -1e30f;
  for (int jj = 0; jj < np; jj++)
    M = fmaxf(M, pml[(base + jj) * 128 + row * 2]);

  float L = 0.0f;
  float a[4] = {0.f, 0.f, 0.f, 0.f};
  for (int jj = 0; jj < np; jj++) {
    const float* mlp = &pml[(base + jj) * 128 + row * 2];
    float wj = __expf(mlp[0] - M);
    L += mlp[1] * wj;
    us4 h = *(const us4*)&pO[(base + jj) * 4096 + row * 64 + c];
#pragma unroll
    for (int e = 0; e < 4; e++) a[e] += wj * h2f(h[e]);
  }
  const float inv = 1.0f / L;
  f32x4 o;
#pragma unroll
  for (int e = 0; e < 4; e++) o[e] = a[e] * inv;
  *(f32x4*)&out[((size_t)b * S_LEN + qt * 64 + row) * 64 + c] = o;
}

// ---------------------------------------------------------------------------
extern "C" void kernel_launch(void* const* d_in, const int* in_sizes, int n_in,
                              void* d_out, int out_size, void* d_ws, size_t ws_size,
                              hipStream_t stream) {
  const float* x1 = (const float*)d_in[0];
  const float* x2 = (const float*)d_in[1];
  const float* Wq = (const float*)d_in[2];
  const float* bq = (const float*)d_in[3];
  const float* Wk = (const float*)d_in[4];
  const float* bk = (const float*)d_in[5];
  const float* Wv = (const float*)d_in[6];
  const float* bv = (const float*)d_in[7];
  const int* amask = (const int*)d_in[8];

  unsigned short* qws = (unsigned short*)d_ws;          // [16384][64] f16
  unsigned short* kws = qws + (size_t)NROW * 64;
  unsigned short* vtws = kws + (size_t)NROW * 64;       // [4][64][4096] f16
  unsigned short* wtT = vtws + (size_t)NROW * 64;       // [3][64][512] f16
  unsigned short* pO = wtT + (size_t)3 * 64 * 512;      // [2048][64][64] f16
  float* pml = (float*)(pO + (size_t)2048 * 4096);      // [2048][64][2] f32
  float* out = (float*)d_out;

  prep_kernel<<<dim3(8, 3), 256, 0, stream>>>(Wq, Wk, Wv, wtT);
  proj_kernel<<<dim3(512, 2), 128, 0, stream>>>(x1, x2, wtT, bq, bk, bv,
                                                qws, kws, vtws);
  attn_part<<<dim3(64, NPMAX, 4), 256, 0, stream>>>(qws, kws, vtws, amask,
                                                    pO, pml);
  combine_kernel<<<dim3(64, 4, 4), 256, 0, stream>>>(pO, pml, amask, out);
}